// Round 6
// baseline (147.746 us; speedup 1.0000x reference)
//
#include <hip/hip_runtime.h>
#include <math.h>

#define BATCH 32
#define SEQ   8192
#define HID   512
#define STRIPES 32                 // pass1 blocks per batch
#define RPB   (SEQ / STRIPES)      // 256 rows per block
#define GPW   32                   // groups per wave (2 rows/group -> 64 rows/wave)
#define DEPTH 4                    // register pipeline depth (groups in flight)

typedef float f4 __attribute__((ext_vector_type(4)));
typedef float f2 __attribute__((ext_vector_type(2)));

// Pass 1: fused attn-dot + raw-attn store + online masked softmax partials.
// NO LDS staging: each wave owns 64 contiguous rows and streams them through
// a 4-deep rotating REGISTER pipeline (all indices static via full unroll).
// The compiler's dataflow inserts counted vmcnt waits; loads stay in flight
// across the outer loop back-edge.
__global__ __launch_bounds__(256, 4) void k_pass1(
    const float* __restrict__ outp, const float* __restrict__ ctx,
    const int* __restrict__ split, float* __restrict__ attn_out,
    float* __restrict__ pacc, float* __restrict__ pmd)
{
  const int tid = threadIdx.x, lane = tid & 63, wave = tid >> 6;
  const int b = blockIdx.x >> 5;          // STRIPES == 32
  const int stripe = blockIdx.x & 31;
  const int sp = split[b];
  const int s_base = stripe * RPB;
  const int w_base = s_base + wave * 64;  // first row of this wave

  const float* ob = outp + b * HID;
  const f4 o0 = *(const f4*)(ob + lane * 4);
  const f4 o1 = *(const f4*)(ob + 256 + lane * 4);

  const float* wb = ctx + ((size_t)b * SEQ + w_base) * HID;   // wave's region
  float* ao = attn_out + (size_t)b * SEQ + w_base;

  // pipeline registers: [stage][row-in-group][half]; lane covers cols
  // 4*lane..4*lane+3 (half 0) and 256+4*lane.. (half 1)
  f4 r[DEPTH][2][2];
#pragma unroll
  for (int ji = 0; ji < DEPTH; ++ji) {
    const float* gp = wb + (size_t)(2 * ji) * HID + lane * 4;
    r[ji][0][0] = *(const f4*)gp;
    r[ji][0][1] = *(const f4*)(gp + 256);
    r[ji][1][0] = *(const f4*)(gp + HID);
    r[ji][1][1] = *(const f4*)(gp + HID + 256);
  }

  float m = -INFINITY, d = 0.f;
  f4 acc0 = {0.f, 0.f, 0.f, 0.f}, acc1 = {0.f, 0.f, 0.f, 0.f};

#define CONSUME(JIDX, C00, C01, C10, C11)                                      \
  {                                                                            \
    float a0, a1;                                                              \
    {                                                                          \
      float v = C00[0]*o0[0] + C00[1]*o0[1] + C00[2]*o0[2] + C00[3]*o0[3]      \
              + C01[0]*o1[0] + C01[1]*o1[1] + C01[2]*o1[2] + C01[3]*o1[3];     \
      _Pragma("unroll")                                                        \
      for (int off = 32; off >= 1; off >>= 1) v += __shfl_xor(v, off, 64);     \
      a0 = v;                                                                  \
    }                                                                          \
    {                                                                          \
      float v = C10[0]*o0[0] + C10[1]*o0[1] + C10[2]*o0[2] + C10[3]*o0[3]      \
              + C11[0]*o1[0] + C11[1]*o1[1] + C11[2]*o1[2] + C11[3]*o1[3];     \
      _Pragma("unroll")                                                        \
      for (int off = 32; off >= 1; off >>= 1) v += __shfl_xor(v, off, 64);     \
      a1 = v;                                                                  \
    }                                                                          \
    if (lane == 0) { f2 st = {a0, a1}; *(f2*)(ao + 2 * (JIDX)) = st; }         \
    {                                                                          \
      const int s0 = w_base + 2 * (JIDX);                                      \
      if (s0 < sp) {                      /* wave-uniform */                   \
        const float nm = fmaxf(m, a0);                                         \
        const float sc = __expf(m - nm);                                       \
        const float w  = __expf(a0 - nm);                                      \
        d = d * sc + w;                                                        \
        acc0 = acc0 * sc + w * C00;                                            \
        acc1 = acc1 * sc + w * C01;                                            \
        m = nm;                                                                \
      }                                                                        \
      if (s0 + 1 < sp) {                                                       \
        const float nm = fmaxf(m, a1);                                         \
        const float sc = __expf(m - nm);                                       \
        const float w  = __expf(a1 - nm);                                      \
        d = d * sc + w;                                                        \
        acc0 = acc0 * sc + w * C10;                                            \
        acc1 = acc1 * sc + w * C11;                                            \
        m = nm;                                                                \
      }                                                                        \
    }                                                                          \
  }

#pragma unroll 1
  for (int jo = 0; jo < GPW / DEPTH - 1; ++jo) {   // 7 iterations
#pragma unroll
    for (int ji = 0; ji < DEPTH; ++ji) {
      const int j = jo * DEPTH + ji;
      const f4 c00 = r[ji][0][0], c01 = r[ji][0][1];
      const f4 c10 = r[ji][1][0], c11 = r[ji][1][1];
      {  // refill stage ji with group j+DEPTH (issued before the compute)
        const float* gp = wb + (size_t)(2 * (j + DEPTH)) * HID + lane * 4;
        r[ji][0][0] = *(const f4*)gp;
        r[ji][0][1] = *(const f4*)(gp + 256);
        r[ji][1][0] = *(const f4*)(gp + HID);
        r[ji][1][1] = *(const f4*)(gp + HID + 256);
      }
      CONSUME(j, c00, c01, c10, c11);
    }
  }
  // tail: consume the last DEPTH groups (no refill)
#pragma unroll
  for (int ji = 0; ji < DEPTH; ++ji) {
    const int j = (GPW - DEPTH) + ji;
    CONSUME(j, r[ji][0][0], r[ji][0][1], r[ji][1][0], r[ji][1][1]);
  }
#undef CONSUME

  // merge 4 wave partials via small LDS
  __shared__ float lacc[4 * HID];
  __shared__ float lmd[8];
  *(f4*)(lacc + wave * HID + lane * 4)       = acc0;
  *(f4*)(lacc + wave * HID + 256 + lane * 4) = acc1;
  if (lane == 0) { lmd[wave * 2] = m; lmd[wave * 2 + 1] = d; }
  __syncthreads();

  const float M = fmaxf(fmaxf(lmd[0], lmd[2]), fmaxf(lmd[4], lmd[6]));
  const size_t pb = (size_t)b * STRIPES + stripe;
  float* pa = pacc + pb * HID;
  if (M == -INFINITY) {
    pa[tid * 2] = 0.f; pa[tid * 2 + 1] = 0.f;
    if (tid == 0) { pmd[pb * 2] = -INFINITY; pmd[pb * 2 + 1] = 0.f; }
  } else {
    float e[4], Dl = 0.f;
#pragma unroll
    for (int wv = 0; wv < 4; ++wv) {
      const float mw = lmd[wv * 2];
      e[wv] = (mw == -INFINITY) ? 0.f : __expf(mw - M);
      Dl += e[wv] * lmd[wv * 2 + 1];
    }
    float s0 = 0.f, s1 = 0.f;
#pragma unroll
    for (int wv = 0; wv < 4; ++wv) {
      s0 += e[wv] * lacc[wv * HID + tid * 2];
      s1 += e[wv] * lacc[wv * HID + tid * 2 + 1];
    }
    pa[tid * 2] = s0; pa[tid * 2 + 1] = s1;
    if (tid == 0) { pmd[pb * 2] = M; pmd[pb * 2 + 1] = Dl; }
  }
}

// Pass 2: block (b,q) -> 64 outputs. 4-way k-split per h (tid = hl*4+part),
// parts: 0,1 -> amix halves of W row; 2 -> det; 3 -> output. LDS bank-padded.
__global__ __launch_bounds__(256) void k_final(
    const float* __restrict__ outp, const float* __restrict__ ctx,
    const int* __restrict__ split, const float* __restrict__ W,
    const float* __restrict__ bias, const float* __restrict__ pacc,
    const float* __restrict__ pmd, float* __restrict__ out0)
{
  const int b = blockIdx.x >> 3, q = blockIdx.x & 7;
  const int tid = threadIdx.x;
  __shared__ float comb[3 * HID + 8];
  float* amixp = comb;                 // [0, 512)
  float* detp  = comb + HID + 4;       // bank offset +4
  float* oupp  = comb + 2 * HID + 8;   // bank offset +8

  float M = -INFINITY;
#pragma unroll
  for (int c = 0; c < STRIPES; ++c) M = fmaxf(M, pmd[(b * STRIPES + c) * 2]);
  float wgt[STRIPES], D = 0.f;
#pragma unroll
  for (int c = 0; c < STRIPES; ++c) {
    const float mw = pmd[(b * STRIPES + c) * 2];
    wgt[c] = (mw == -INFINITY) ? 0.f : __expf(mw - M);
    D += wgt[c] * pmd[(b * STRIPES + c) * 2 + 1];
  }
  const float invD = 1.f / D;
  const int sp = split[b];
#pragma unroll
  for (int col = tid; col < HID; col += 256) {
    float s = 0.f;
#pragma unroll
    for (int c = 0; c < STRIPES; ++c)
      s += wgt[c] * pacc[((size_t)(b * STRIPES + c)) * HID + col];
    amixp[col] = s * invD;
    detp[col]  = ctx[((size_t)b * SEQ + sp) * HID + col];
    oupp[col]  = outp[b * HID + col];
  }
  __syncthreads();

  const int hl = tid >> 2, part = tid & 3;
  const int h = q * 64 + hl;
  const float* wr = W + (size_t)h * (4 * HID) + part * HID;
  const float* src = (part == 2) ? detp : (part == 3 ? oupp : amixp);
  float acc = 0.f;
#pragma unroll 4
  for (int k0 = 0; k0 < HID; k0 += 4) {
    const f4 w = *(const f4*)(wr + k0);
    const f4 x = *(const f4*)(src + k0);
    acc += w[0]*x[0] + w[1]*x[1] + w[2]*x[2] + w[3]*x[3];
  }
  acc += __shfl_xor(acc, 1, 64);
  acc += __shfl_xor(acc, 2, 64);
  if (part == 0) out0[b * HID + h] = tanhf(acc + bias[h]);
}

extern "C" void kernel_launch(void* const* d_in, const int* in_sizes, int n_in,
                              void* d_out, int out_size, void* d_ws, size_t ws_size,
                              hipStream_t stream)
{
  const float* outp = (const float*)d_in[0]; // [B,1,H] f32
  const float* ctx  = (const float*)d_in[1]; // [B,S,H] f32
  const int*   spl  = (const int*)d_in[2];   // [B] int32
  const float* W    = (const float*)d_in[3]; // [H,4H] f32
  const float* bias = (const float*)d_in[4]; // [H] f32

  float* out0   = (float*)d_out;                        // B*H f32
  float* attn_o = out0 + (size_t)BATCH * HID;           // B*S f32

  float* pacc = (float*)d_ws;                           // B*STRIPES*HID f32 (2 MB)
  float* pmd  = pacc + (size_t)BATCH * STRIPES * HID;   // B*STRIPES*2 f32

  k_pass1<<<BATCH * STRIPES, 256, 0, stream>>>(outp, ctx, spl, attn_o, pacc, pmd);
  k_final<<<BATCH * 8,       256, 0, stream>>>(outp, ctx, spl, W, bias, pacc, pmd, out0);
}

// Round 7
// 131.775 us; speedup vs baseline: 1.1212x; 1.1212x over previous
//
#include <hip/hip_runtime.h>
#include <math.h>

#define BATCH 32
#define SEQ   8192
#define HID   512
#define STRIPES 32                        // pass1 blocks per batch
#define CR    8                           // chunk rows (16 KB per chunk)
#define NCHUNK (SEQ / (STRIPES * CR))     // 32 chunks per stripe (strided)

typedef float f4 __attribute__((ext_vector_type(4)));
typedef float f2 __attribute__((ext_vector_type(2)));

#define VMWAIT(N) do { asm volatile("s_waitcnt vmcnt(" #N ")" ::: "memory"); \
                       __builtin_amdgcn_sched_barrier(0); } while (0)
#define LGKMWAIT0 do { asm volatile("s_waitcnt lgkmcnt(0)" ::: "memory"); \
                       __builtin_amdgcn_sched_barrier(0); } while (0)

__device__ __forceinline__ void gload_lds(const float* g, float* l) {
  __builtin_amdgcn_global_load_lds(
      (const __attribute__((address_space(1))) void*)g,
      (__attribute__((address_space(3))) void*)l, 16, 0, 0);
}

// Pass 1: fused attn-dot + raw-attn store + online masked softmax partials.
// STRIDED chunk ownership: stripe s owns chunks {s, s+32, ...} so at any
// instant the 32 stripes of a batch cover one contiguous 512KB span ->
// uniform HBM channel coverage (fixes phase-locked channel hotspots).
// Per-wave private pipeline, counted vmcnt, no main-loop barriers.
__global__ __launch_bounds__(256, 4) void k_pass1(
    const float* __restrict__ outp, const float* __restrict__ ctx,
    const int* __restrict__ split, float* __restrict__ attn_out,
    float* __restrict__ pacc, float* __restrict__ pmd)
{
  __shared__ float lds[2][CR][HID];       // 2 x 16 KB
  const int tid = threadIdx.x, lane = tid & 63, wave = tid >> 6;
  const int b = blockIdx.x >> 5;          // STRIPES == 32
  const int stripe = blockIdx.x & 31;
  const int sp = split[b];

  const float* ob = outp + b * HID + lane * 8;
  const f4 o0 = *(const f4*)ob;
  const f4 o1 = *(const f4*)(ob + 4);

  const float* bbase = ctx + (size_t)b * SEQ * HID;
  float* ao_b = attn_out + (size_t)b * SEQ;

  // chunk c of this stripe starts at row (c*STRIPES + stripe)*CR
#define CHUNK_ROW(c) (((c) * STRIPES + stripe) * CR)

  // prologue: chunk0 -> buf0, chunk1 -> buf1 (own wave region: rows 2w..2w+1)
#pragma unroll
  for (int i = 0; i < 4; ++i) {
    const int o = (wave * 4 + i) * 256;
    gload_lds(bbase + (size_t)CHUNK_ROW(0) * HID + o + lane * 4, &lds[0][0][0] + o);
  }
#pragma unroll
  for (int i = 0; i < 4; ++i) {
    const int o = (wave * 4 + i) * 256;
    gload_lds(bbase + (size_t)CHUNK_ROW(1) * HID + o + lane * 4, &lds[1][0][0] + o);
  }

  float m = -INFINITY, d = 0.f;
  f4 acc0 = {0.f, 0.f, 0.f, 0.f}, acc1 = {0.f, 0.f, 0.f, 0.f};

  // vmcnt ledger (in-order retirement), ops/iter: st(c) then 4x L(c+2):
  //   iter 0: queue = L0(4),L1(4)                      -> wait 4
  //   iter c: queue = st(c-2),L(c)4,st(c-1),L(c+1)4=10 -> wait 5
  //   last  : queue = st(c-2),L(c)4,st(c-1)            -> wait 1
#pragma unroll 1
  for (int c = 0; c < NCHUNK; ++c) {
    if (c == 0)                 VMWAIT(4);
    else if (c == NCHUNK - 1)   VMWAIT(1);
    else                        VMWAIT(5);

    const int cur = c & 1;
    const int row0 = CHUNK_ROW(c);        // global row of this chunk's row 0
    f4 c0[2], c1[2];
#pragma unroll
    for (int k = 0; k < 2; ++k) {
      const float* rp = &lds[cur][wave * 2 + k][lane * 8];
      c0[k] = *(const f4*)rp;
      c1[k] = *(const f4*)(rp + 4);
    }
    LGKMWAIT0;   // rows in regs -> safe to overwrite buf[cur]

    float a2[2];
#pragma unroll
    for (int k = 0; k < 2; ++k) {
      float v = o0[0]*c0[k][0] + o0[1]*c0[k][1] + o0[2]*c0[k][2] + o0[3]*c0[k][3]
              + o1[0]*c1[k][0] + o1[1]*c1[k][1] + o1[2]*c1[k][2] + o1[3]*c1[k][3];
#pragma unroll
      for (int off = 32; off >= 1; off >>= 1) v += __shfl_xor(v, off, 64);
      a2[k] = v;
    }
    if (lane == 0) {
      f2 st = {a2[0], a2[1]};
      *(f2*)(ao_b + row0 + wave * 2) = st;   // raw attn (1 vmem store/iter)
    }

    if (c + 2 < NCHUNK) {       // prefetch chunk c+2 into buf[cur]
      const float* src = bbase + (size_t)CHUNK_ROW(c + 2) * HID;
      float* dst = &lds[cur][0][0];
#pragma unroll
      for (int i = 0; i < 4; ++i) {
        const int o = (wave * 4 + i) * 256;
        gload_lds(src + o + lane * 4, dst + o);
      }
    }

#pragma unroll
    for (int k = 0; k < 2; ++k) {
      const int s = row0 + wave * 2 + k;     // wave-uniform branch
      if (s < sp) {
        const float v  = a2[k];
        const float nm = fmaxf(m, v);
        const float sc = __expf(m - nm);
        const float w  = __expf(v - nm);
        d = d * sc + w;
        acc0 = acc0 * sc + w * c0[k];
        acc1 = acc1 * sc + w * c1[k];
        m = nm;
      }
    }
  }
#undef CHUNK_ROW

  __syncthreads();                        // all waves done with buffers
  float* lacc = &lds[0][0][0];            // [4][HID] (16 KB buffer reused)
  float* lmd  = &lds[1][0][0];            // [4][2]
  *(f4*)(lacc + wave * HID + lane * 8)     = acc0;
  *(f4*)(lacc + wave * HID + lane * 8 + 4) = acc1;
  if (lane == 0) { lmd[wave * 2] = m; lmd[wave * 2 + 1] = d; }
  __syncthreads();

  const float M = fmaxf(fmaxf(lmd[0], lmd[2]), fmaxf(lmd[4], lmd[6]));
  const size_t pb = (size_t)b * STRIPES + stripe;
  float* pa = pacc + pb * HID;
  if (M == -INFINITY) {
    pa[tid * 2] = 0.f; pa[tid * 2 + 1] = 0.f;
    if (tid == 0) { pmd[pb * 2] = -INFINITY; pmd[pb * 2 + 1] = 0.f; }
  } else {
    float e[4], Dl = 0.f;
#pragma unroll
    for (int wv = 0; wv < 4; ++wv) {
      const float mw = lmd[wv * 2];
      e[wv] = (mw == -INFINITY) ? 0.f : __expf(mw - M);
      Dl += e[wv] * lmd[wv * 2 + 1];
    }
    float s0 = 0.f, s1 = 0.f;
#pragma unroll
    for (int wv = 0; wv < 4; ++wv) {
      s0 += e[wv] * lacc[wv * HID + tid * 2];
      s1 += e[wv] * lacc[wv * HID + tid * 2 + 1];
    }
    pa[tid * 2] = s0; pa[tid * 2 + 1] = s1;
    if (tid == 0) { pmd[pb * 2] = M; pmd[pb * 2 + 1] = Dl; }
  }
}

// Pass 2: block (b,q) -> 64 outputs. 4-way k-split per h (tid = hl*4+part),
// parts: 0,1 -> amix halves of W row; 2 -> det; 3 -> output. LDS bank-padded.
__global__ __launch_bounds__(256) void k_final(
    const float* __restrict__ outp, const float* __restrict__ ctx,
    const int* __restrict__ split, const float* __restrict__ W,
    const float* __restrict__ bias, const float* __restrict__ pacc,
    const float* __restrict__ pmd, float* __restrict__ out0)
{
  const int b = blockIdx.x >> 3, q = blockIdx.x & 7;
  const int tid = threadIdx.x;
  __shared__ float comb[3 * HID + 8];
  float* amixp = comb;                 // [0, 512)
  float* detp  = comb + HID + 4;       // bank offset +4
  float* oupp  = comb + 2 * HID + 8;   // bank offset +8

  float M = -INFINITY;
#pragma unroll
  for (int c = 0; c < STRIPES; ++c) M = fmaxf(M, pmd[(b * STRIPES + c) * 2]);
  float wgt[STRIPES], D = 0.f;
#pragma unroll
  for (int c = 0; c < STRIPES; ++c) {
    const float mw = pmd[(b * STRIPES + c) * 2];
    wgt[c] = (mw == -INFINITY) ? 0.f : __expf(mw - M);
    D += wgt[c] * pmd[(b * STRIPES + c) * 2 + 1];
  }
  const float invD = 1.f / D;
  const int sp = split[b];
#pragma unroll
  for (int col = tid; col < HID; col += 256) {
    float s = 0.f;
#pragma unroll
    for (int c = 0; c < STRIPES; ++c)
      s += wgt[c] * pacc[((size_t)(b * STRIPES + c)) * HID + col];
    amixp[col] = s * invD;
    detp[col]  = ctx[((size_t)b * SEQ + sp) * HID + col];
    oupp[col]  = outp[b * HID + col];
  }
  __syncthreads();

  const int hl = tid >> 2, part = tid & 3;
  const int h = q * 64 + hl;
  const float* wr = W + (size_t)h * (4 * HID) + part * HID;
  const float* src = (part == 2) ? detp : (part == 3 ? oupp : amixp);
  float acc = 0.f;
#pragma unroll 4
  for (int k0 = 0; k0 < HID; k0 += 4) {
    const f4 w = *(const f4*)(wr + k0);
    const f4 x = *(const f4*)(src + k0);
    acc += w[0]*x[0] + w[1]*x[1] + w[2]*x[2] + w[3]*x[3];
  }
  acc += __shfl_xor(acc, 1, 64);
  acc += __shfl_xor(acc, 2, 64);
  if (part == 0) out0[b * HID + h] = tanhf(acc + bias[h]);
}

extern "C" void kernel_launch(void* const* d_in, const int* in_sizes, int n_in,
                              void* d_out, int out_size, void* d_ws, size_t ws_size,
                              hipStream_t stream)
{
  const float* outp = (const float*)d_in[0]; // [B,1,H] f32
  const float* ctx  = (const float*)d_in[1]; // [B,S,H] f32
  const int*   spl  = (const int*)d_in[2];   // [B] int32
  const float* W    = (const float*)d_in[3]; // [H,4H] f32
  const float* bias = (const float*)d_in[4]; // [H] f32

  float* out0   = (float*)d_out;                        // B*H f32
  float* attn_o = out0 + (size_t)BATCH * HID;           // B*S f32

  float* pacc = (float*)d_ws;                           // B*STRIPES*HID f32 (2 MB)
  float* pmd  = pacc + (size_t)BATCH * STRIPES * HID;   // B*STRIPES*2 f32

  k_pass1<<<BATCH * STRIPES, 256, 0, stream>>>(outp, ctx, spl, attn_o, pacc, pmd);
  k_final<<<BATCH * 8,       256, 0, stream>>>(outp, ctx, spl, W, bias, pacc, pmd, out0);
}